// Round 9
// baseline (595.620 us; speedup 1.0000x reference)
//
#include <hip/hip_runtime.h>
#include <hip/hip_bf16.h>

#define NWIN 4096
#define SCALE 0.17677669529663687f

typedef __attribute__((ext_vector_type(8))) short bf16x8;
typedef __attribute__((ext_vector_type(4))) float f32x4;
typedef __attribute__((ext_vector_type(4))) unsigned short u16x4;
typedef __attribute__((ext_vector_type(8))) unsigned short u16x8;

__device__ __forceinline__ unsigned short f2bf(float f) {
    __hip_bfloat16 h = __float2bfloat16(f);
    return *reinterpret_cast<unsigned short*>(&h);
}
__device__ __forceinline__ f32x4 MF(bf16x8 a, bf16x8 b, f32x4 c) {
    return __builtin_amdgcn_mfma_f32_16x16x32_bf16(a, b, c, 0, 0, 0);
}
__device__ __forceinline__ bf16x8 LD8(const unsigned short* p) {
    return *reinterpret_cast<const bf16x8*>(p);
}

// ---------- prologue: weights -> bf16 [N][K] in d_ws ----
// COALESCED reads (row-major in), scatter writes (posted, L2-merged).
// ws layout (bf16 elems): qkv^T [288][96] @0 ; proj^T [96][96] @27648 ;
//                         fc1^T [384][96] @36864 ; fc2^T [96][384] @73728
__global__ __launch_bounds__(512) void k_prep(
    const float* __restrict__ qkvw, const float* __restrict__ projw,
    const float* __restrict__ fc1w, const float* __restrict__ fc2w,
    unsigned short* __restrict__ ws)
{
    int i = blockIdx.x*512 + threadIdx.x;
    if (i >= 110592) return;
    if (i < 27648)      { int k = i/288,        n = i%288; ws[n*96 + k]         = f2bf(qkvw[i]); }
    else if (i < 36864) { int j = i-27648;  int k = j/96,  n = j%96;  ws[27648 + n*96 + k]  = f2bf(projw[j]); }
    else if (i < 73728) { int j = i-36864;  int k = j/384, n = j%384; ws[36864 + n*96 + k]  = f2bf(fc1w[j]); }
    else                { int j = i-73728;  int k = j/96,  n = j%96;  ws[73728 + n*384 + k] = f2bf(fc2w[j]); }
}

// ---------- fused per-window kernel: 512 thr (8 waves), dyn LDS 112784 B ------
// Weights (B-fragments) are read straight from global (L2-resident, 221 KB).
// LDS map (bytes):
//   0      s_res  f32 [64][100]   25600   (x, then x1)        persistent
//   25600  s_a    bf16 [64][104]  13312   (LN1 -> attn-out -> LN2)
//   38912  s_bias f32 [675]        2700
//   41616  s_s    f32 [64][68]    17408   (scores, scale+bias folded)
//   59024  s_p    bf16 [64][72]    9216   (softmax P)
//   68240  s_q    bf16 [3][64][40] 15360  \
//   83600  s_k    bf16 [3][64][40] 15360   } s_h bf16 [64][200] (25600) aliases s_q+s_k in MLP phase
//   98960  s_vt   bf16 [3][32][72] 13824  /  -> end 112784
__global__ __launch_bounds__(512) void k_fused(
    const float* __restrict__ x,
    const float* __restrict__ n1g, const float* __restrict__ n1b,
    const float* __restrict__ qkv_b, const float* __restrict__ proj_b,
    const float* __restrict__ btab,
    const float* __restrict__ n2g, const float* __restrict__ n2b,
    const float* __restrict__ fc1b, const float* __restrict__ fc2b,
    const unsigned short* __restrict__ wbf, float* __restrict__ out)
{
    extern __shared__ char smem[];
    float*          s_res  = (float*)smem;
    unsigned short* s_a    = (unsigned short*)(smem + 25600);
    float*          s_bias = (float*)(smem + 38912);
    float*          s_s    = (float*)(smem + 41616);
    unsigned short* s_p    = (unsigned short*)(smem + 59024);
    unsigned short* s_q    = (unsigned short*)(smem + 68240);
    unsigned short* s_k    = (unsigned short*)(smem + 83600);
    unsigned short* s_vt   = (unsigned short*)(smem + 98960);
    unsigned short* s_h    = (unsigned short*)(smem + 68240);   // MLP alias

    const int tid  = threadIdx.x;
    const int wid  = tid >> 6, lane = tid & 63, l16 = lane & 15, l4 = lane >> 4;
    const int wb   = blockIdx.x;
    const int b    = wb >> 10, wrem = wb & 1023, wy = wrem >> 5, wx = wrem & 31;
    const long base = ((long)(b*256 + wy*8)*256 + (long)(wx*8))*96;
    const int mtile = wid >> 1;      // row-tile for every GEMM phase
    const int nh    = wid & 1;       // column half

    // ---- Phase 0: x window -> s_res (f32, pitch 100); rel-bias -> s_bias
    for (int i = tid; i < 64*24; i += 512) {
        int tok = i / 24, seg = i % 24;
        const float4 v = *reinterpret_cast<const float4*>(
            x + base + (long)(((tok >> 3) << 8) + (tok & 7))*96 + seg*4);
        *reinterpret_cast<float4*>(s_res + tok*100 + seg*4) = v;
    }
    for (int i = tid; i < 675; i += 512) s_bias[i] = btab[i];
    __syncthreads();

    // ---- Phase 1: LN1 -> s_a (vectorized)
    {
        const int tok = tid >> 3, part = tid & 7;
        const float* rp = s_res + tok*100 + part*12;
        float4 v0 = *reinterpret_cast<const float4*>(rp);
        float4 v1 = *reinterpret_cast<const float4*>(rp + 4);
        float4 v2 = *reinterpret_cast<const float4*>(rp + 8);
        float r[12] = {v0.x,v0.y,v0.z,v0.w, v1.x,v1.y,v1.z,v1.w, v2.x,v2.y,v2.z,v2.w};
        float s1 = 0.f, s2 = 0.f;
        #pragma unroll
        for (int i = 0; i < 12; ++i) { s1 += r[i]; s2 += r[i]*r[i]; }
        s1 += __shfl_xor(s1,1); s2 += __shfl_xor(s2,1);
        s1 += __shfl_xor(s1,2); s2 += __shfl_xor(s2,2);
        s1 += __shfl_xor(s1,4); s2 += __shfl_xor(s2,4);
        float mu = s1*(1.f/96.f), var = s2*(1.f/96.f) - mu*mu;
        float rs = rsqrtf(var + 1e-5f);
        unsigned short* wp = s_a + tok*104 + part*12;
        #pragma unroll
        for (int q = 0; q < 3; ++q) {
            u16x4 pk;
            #pragma unroll
            for (int j = 0; j < 4; ++j) {
                int c = part*12 + q*4 + j;
                pk[j] = f2bf((r[q*4+j]-mu)*rs*n1g[c] + n1b[c]);
            }
            *reinterpret_cast<u16x4*>(wp + q*4) = pk;
        }
    }
    __syncthreads();

    // ---- Phase 2: QKV GEMM (64x288xK96), B-frags straight from L2
    {
        const unsigned short* ap = s_a + (mtile*16 + l16)*104 + l4*8;
        const bf16x8 a0 = LD8(ap), a1 = LD8(ap+32), a2 = LD8(ap+64);
        #pragma unroll
        for (int u = 0; u < 9; ++u) {
            const int ntile = nh*9 + u;
            const unsigned short* bp = wbf + (ntile*16 + l16)*96 + l4*8;
            f32x4 acc = {0.f,0.f,0.f,0.f};
            acc = MF(a0, LD8(bp),    acc);
            acc = MF(a1, LD8(bp+32), acc);
            acc = MF(a2, LD8(bp+64), acc);
            const int col = ntile*16 + l16;
            const float bv = qkv_b[col];
            const int sel = col/96, hc = col%96, h = hc >> 5, d = hc & 31;
            if (sel < 2) {
                unsigned short* q = (sel == 0 ? s_q : s_k) + h*2560 + d;
                #pragma unroll
                for (int r = 0; r < 4; ++r)
                    q[(mtile*16 + l4*4 + r)*40] = f2bf(acc[r] + bv);
            } else {
                u16x4 pk;
                #pragma unroll
                for (int r = 0; r < 4; ++r) pk[r] = f2bf(acc[r] + bv);
                *reinterpret_cast<u16x4*>(s_vt + h*2304 + d*72 + mtile*16 + l4*4) = pk;
            }
        }
    }
    __syncthreads();

    // ---- Phase 3: pipelined heads: {QK^T(h) || PV(h-1)} -> bar -> softmax(h) -> bar
    for (int h = 0; h < 3; ++h) {
        {   // QK^T head h, scale+bias folded into epilogue
            const unsigned short* ap = s_q + h*2560 + (mtile*16 + l16)*40 + l4*8;
            const bf16x8 af = LD8(ap);
            #pragma unroll
            for (int u = 0; u < 2; ++u) {
                const int ntile = nh*2 + u;
                const unsigned short* bp = s_k + h*2560 + (ntile*16 + l16)*40 + l4*8;
                f32x4 acc = {0.f,0.f,0.f,0.f};
                acc = MF(af, LD8(bp), acc);
                const int col = ntile*16 + l16;
                const int yj = col >> 3, xj = col & 7;
                #pragma unroll
                for (int r = 0; r < 4; ++r) {
                    const int row = mtile*16 + l4*4 + r;
                    const int yi = row >> 3, xi = row & 7;
                    const int ridx = (yi-yj+7)*15 + (xi-xj+7);
                    s_s[row*68 + col] = acc[r]*SCALE + s_bias[ridx*3 + h];
                }
            }
        }
        if (h > 0) {   // PV head h-1 (overlaps with QK^T h)
            const unsigned short* ap = s_p + (mtile*16 + l16)*72 + l4*8;
            const bf16x8 a0 = LD8(ap), a1 = LD8(ap+32);
            const unsigned short* bp = s_vt + (h-1)*2304 + (nh*16 + l16)*72 + l4*8;
            f32x4 acc = {0.f,0.f,0.f,0.f};
            acc = MF(a0, LD8(bp),    acc);
            acc = MF(a1, LD8(bp+32), acc);
            #pragma unroll
            for (int r = 0; r < 4; ++r)
                s_a[(mtile*16 + l4*4 + r)*104 + (h-1)*32 + nh*16 + l16] = f2bf(acc[r]);
        }
        __syncthreads();
        {   // softmax head h (vectorized reads, one 16B P write)
            const int i = tid >> 3, part = tid & 7;
            const float* sp = s_s + i*68 + part*8;
            float4 v0 = *reinterpret_cast<const float4*>(sp);
            float4 v1 = *reinterpret_cast<const float4*>(sp + 4);
            float v[8] = {v0.x,v0.y,v0.z,v0.w, v1.x,v1.y,v1.z,v1.w};
            float m = v[0];
            #pragma unroll
            for (int u = 1; u < 8; ++u) m = fmaxf(m, v[u]);
            m = fmaxf(m, __shfl_xor(m,1)); m = fmaxf(m, __shfl_xor(m,2)); m = fmaxf(m, __shfl_xor(m,4));
            float s = 0.f;
            #pragma unroll
            for (int u = 0; u < 8; ++u) { v[u] = __expf(v[u] - m); s += v[u]; }
            s += __shfl_xor(s,1); s += __shfl_xor(s,2); s += __shfl_xor(s,4);
            const float inv = 1.f/s;
            u16x8 pk;
            #pragma unroll
            for (int u = 0; u < 8; ++u) pk[u] = f2bf(v[u]*inv);
            *reinterpret_cast<u16x8*>(s_p + i*72 + part*8) = pk;
        }
        __syncthreads();
    }
    {   // PV head 2 (epilogue of the pipeline)
        const unsigned short* ap = s_p + (mtile*16 + l16)*72 + l4*8;
        const bf16x8 a0 = LD8(ap), a1 = LD8(ap+32);
        const unsigned short* bp = s_vt + 2*2304 + (nh*16 + l16)*72 + l4*8;
        f32x4 acc = {0.f,0.f,0.f,0.f};
        acc = MF(a0, LD8(bp),    acc);
        acc = MF(a1, LD8(bp+32), acc);
        #pragma unroll
        for (int r = 0; r < 4; ++r)
            s_a[(mtile*16 + l4*4 + r)*104 + 2*32 + nh*16 + l16] = f2bf(acc[r]);
    }
    __syncthreads();

    // ---- Phase 4: proj (64x96xK96) + residual -> s_res becomes x1
    {
        const unsigned short* ap = s_a + (mtile*16 + l16)*104 + l4*8;
        const bf16x8 a0 = LD8(ap), a1 = LD8(ap+32), a2 = LD8(ap+64);
        #pragma unroll
        for (int u = 0; u < 3; ++u) {
            const int ntile = nh*3 + u;
            const unsigned short* bp = wbf + 27648 + (ntile*16 + l16)*96 + l4*8;
            f32x4 acc = {0.f,0.f,0.f,0.f};
            acc = MF(a0, LD8(bp),    acc);
            acc = MF(a1, LD8(bp+32), acc);
            acc = MF(a2, LD8(bp+64), acc);
            const int c = ntile*16 + l16;
            const float pb = proj_b[c];
            #pragma unroll
            for (int r = 0; r < 4; ++r) {
                const int tok = mtile*16 + l4*4 + r;
                s_res[tok*100 + c] += acc[r] + pb;
            }
        }
    }
    __syncthreads();

    // ---- Phase 5: LN2 -> s_a (vectorized)
    {
        const int tok = tid >> 3, part = tid & 7;
        const float* rp = s_res + tok*100 + part*12;
        float4 v0 = *reinterpret_cast<const float4*>(rp);
        float4 v1 = *reinterpret_cast<const float4*>(rp + 4);
        float4 v2 = *reinterpret_cast<const float4*>(rp + 8);
        float r[12] = {v0.x,v0.y,v0.z,v0.w, v1.x,v1.y,v1.z,v1.w, v2.x,v2.y,v2.z,v2.w};
        float s1 = 0.f, s2 = 0.f;
        #pragma unroll
        for (int i = 0; i < 12; ++i) { s1 += r[i]; s2 += r[i]*r[i]; }
        s1 += __shfl_xor(s1,1); s2 += __shfl_xor(s2,1);
        s1 += __shfl_xor(s1,2); s2 += __shfl_xor(s2,2);
        s1 += __shfl_xor(s1,4); s2 += __shfl_xor(s2,4);
        float mu = s1*(1.f/96.f), var = s2*(1.f/96.f) - mu*mu;
        float rs = rsqrtf(var + 1e-5f);
        unsigned short* wp = s_a + tok*104 + part*12;
        #pragma unroll
        for (int q = 0; q < 3; ++q) {
            u16x4 pk;
            #pragma unroll
            for (int j = 0; j < 4; ++j) {
                int c = part*12 + q*4 + j;
                pk[j] = f2bf((r[q*4+j]-mu)*rs*n2g[c] + n2b[c]);
            }
            *reinterpret_cast<u16x4*>(wp + q*4) = pk;
        }
    }
    __syncthreads();

    // ---- Phase 6: MLP in 2 hidden chunks of 192, weights from L2
    f32x4 macc[3];
    #pragma unroll
    for (int u = 0; u < 3; ++u) macc[u] = (f32x4){0.f,0.f,0.f,0.f};

    for (int ch = 0; ch < 2; ++ch) {
        {   // fc1 (64x192xK96) + sigmoid-form GELU -> s_h
            const unsigned short* ap = s_a + (mtile*16 + l16)*104 + l4*8;
            const bf16x8 a0 = LD8(ap), a1 = LD8(ap+32), a2 = LD8(ap+64);
            #pragma unroll
            for (int u = 0; u < 6; ++u) {
                const int ntile = nh*6 + u;
                const int hcol = ntile*16 + l16;
                const unsigned short* bp = wbf + 36864 + (ch*192 + hcol)*96 + l4*8;
                f32x4 acc = {0.f,0.f,0.f,0.f};
                acc = MF(a0, LD8(bp),    acc);
                acc = MF(a1, LD8(bp+32), acc);
                acc = MF(a2, LD8(bp+64), acc);
                const float fb = fc1b[ch*192 + hcol];
                #pragma unroll
                for (int r = 0; r < 4; ++r) {
                    float v = acc[r] + fb;
                    float g = v / (1.f + __expf(-1.5957691216057308f*(v + 0.044715f*v*v*v)));
                    s_h[(mtile*16 + l4*4 + r)*200 + hcol] = f2bf(g);
                }
            }
        }
        __syncthreads();
        {   // fc2 partial (64x96xK192), accumulate across chunks
            const unsigned short* ap = s_h + (mtile*16 + l16)*200 + l4*8;
            bf16x8 af[6];
            #pragma unroll
            for (int kc = 0; kc < 6; ++kc) af[kc] = LD8(ap + kc*32);
            #pragma unroll
            for (int u = 0; u < 3; ++u) {
                const int n = (nh*3 + u)*16 + l16;
                const unsigned short* bp = wbf + 73728 + n*384 + ch*192 + l4*8;
                #pragma unroll
                for (int kc = 0; kc < 6; ++kc)
                    macc[u] = MF(af[kc], LD8(bp + kc*32), macc[u]);
            }
        }
        if (ch == 0) __syncthreads();   // s_h rewritten by ch1 fc1
    }

    // ---- final: out = x1 + mlp + fc2_b
    {
        #pragma unroll
        for (int u = 0; u < 3; ++u) {
            const int c = (nh*3 + u)*16 + l16;
            const float fb = fc2b[c];
            #pragma unroll
            for (int r = 0; r < 4; ++r) {
                const int tok = mtile*16 + l4*4 + r;
                out[base + (long)(((tok >> 3) << 8) + (tok & 7))*96 + c] =
                    s_res[tok*100 + c] + macc[u][r] + fb;
            }
        }
    }
}

extern "C" void kernel_launch(void* const* d_in, const int* in_sizes, int n_in,
                              void* d_out, int out_size, void* d_ws, size_t ws_size,
                              hipStream_t stream) {
    (void)in_sizes; (void)n_in; (void)out_size; (void)ws_size;
    const float* x     = (const float*)d_in[0];
    const float* n1g   = (const float*)d_in[1];
    const float* n1b   = (const float*)d_in[2];
    const float* qkvw  = (const float*)d_in[3];
    const float* qkvb  = (const float*)d_in[4];
    const float* projw = (const float*)d_in[5];
    const float* projb = (const float*)d_in[6];
    const float* btab  = (const float*)d_in[7];
    const float* n2g   = (const float*)d_in[8];
    const float* n2b   = (const float*)d_in[9];
    const float* fc1w  = (const float*)d_in[10];
    const float* fc1b  = (const float*)d_in[11];
    const float* fc2w  = (const float*)d_in[12];
    const float* fc2b  = (const float*)d_in[13];
    float* out = (float*)d_out;
    unsigned short* ws = (unsigned short*)d_ws;

    hipFuncSetAttribute(reinterpret_cast<const void*>(k_fused),
                        hipFuncAttributeMaxDynamicSharedMemorySize, 112784);

    k_prep<<<dim3(216), dim3(512), 0, stream>>>(qkvw, projw, fc1w, fc2w, ws);
    k_fused<<<dim3(NWIN), dim3(512), 112784, stream>>>(
        x, n1g, n1b, qkvb, projb, btab, n2g, n2b, fc1b, fc2b, ws, out);
}

// Round 10
// 486.506 us; speedup vs baseline: 1.2243x; 1.2243x over previous
//
#include <hip/hip_runtime.h>
#include <hip/hip_bf16.h>

#define NWIN 4096
#define SCALE 0.17677669529663687f

typedef __attribute__((ext_vector_type(8))) short bf16x8;
typedef __attribute__((ext_vector_type(4))) float f32x4;
typedef __attribute__((ext_vector_type(4))) unsigned short u16x4;
typedef __attribute__((ext_vector_type(8))) unsigned short u16x8;

__device__ __forceinline__ unsigned short f2bf(float f) {
    __hip_bfloat16 h = __float2bfloat16(f);
    return *reinterpret_cast<unsigned short*>(&h);
}
__device__ __forceinline__ f32x4 MF(bf16x8 a, bf16x8 b, f32x4 c) {
    return __builtin_amdgcn_mfma_f32_16x16x32_bf16(a, b, c, 0, 0, 0);
}
__device__ __forceinline__ bf16x8 LD8(const unsigned short* p) {
    return *reinterpret_cast<const bf16x8*>(p);
}

// ---------- prologue: weights -> bf16 [N][K] in d_ws (coalesced reads) ----
// ws layout (bf16 elems): qkv^T [288][96] @0 ; proj^T [96][96] @27648 ;
//                         fc1^T [384][96] @36864 ; fc2^T [96][384] @73728
__global__ __launch_bounds__(512) void k_prep(
    const float* __restrict__ qkvw, const float* __restrict__ projw,
    const float* __restrict__ fc1w, const float* __restrict__ fc2w,
    unsigned short* __restrict__ ws)
{
    int i = blockIdx.x*512 + threadIdx.x;
    if (i >= 110592) return;
    if (i < 27648)      { int k = i/288,        n = i%288; ws[n*96 + k]         = f2bf(qkvw[i]); }
    else if (i < 36864) { int j = i-27648;  int k = j/96,  n = j%96;  ws[27648 + n*96 + k]  = f2bf(projw[j]); }
    else if (i < 73728) { int j = i-36864;  int k = j/384, n = j%384; ws[36864 + n*96 + k]  = f2bf(fc1w[j]); }
    else                { int j = i-73728;  int k = j/96,  n = j%96;  ws[73728 + n*384 + k] = f2bf(fc2w[j]); }
}

// ---------- fused per-window kernel: 512 thr (8 waves), dyn LDS 162816 B ------
// Weights staged in LDS (padded pitch 104/200 -> ~2-way conflicts, free).
// LDS map (bytes):
//   0      s_res  f32 [64][100]           25600   persistent (x -> x1)
//   25600  s_a    bf16 [64][104]          13312   LN1 -> attn-out -> LN2
//   38912  s_w    multiplexed:
//            P2:  qkv^T bf16 [288][104]   59904   (..98816)
//            P3+: proj^T bf16 [96][104]   19968   (..58880, staged under QK^T h0)
//            P6:  fc1 ch bf16 [192][104]  39936   (..78848)
//     alias during P3 (qkv^T dead):
//          61584  s_s   f32 [64][68]      17408   (..78992)
//          78992  s_p   bf16 [64][72]      9216   (..88208)
//   98816  s_q    bf16 [3][64][40]        15360   (..114176)
//   114176 s_k    bf16 [3][64][40]        15360   (..129536)
//   129536 s_vt   bf16 [3][32][72]        13824   (..143360)
//   143360 s_bias f32 [675]                2700   (..146060)
//     alias during P6 (attn dead):
//          98816  s_h   bf16 [64][200]    25600   (..124416)
//          124416 s_w2  bf16 [96][200]    38400   (..162816)
__global__ __launch_bounds__(512) void k_fused(
    const float* __restrict__ x,
    const float* __restrict__ n1g, const float* __restrict__ n1b,
    const float* __restrict__ qkv_b, const float* __restrict__ proj_b,
    const float* __restrict__ btab,
    const float* __restrict__ n2g, const float* __restrict__ n2b,
    const float* __restrict__ fc1b, const float* __restrict__ fc2b,
    const unsigned short* __restrict__ wbf, float* __restrict__ out)
{
    extern __shared__ char smem[];
    float*          s_res  = (float*)smem;
    unsigned short* s_a    = (unsigned short*)(smem + 25600);
    unsigned short* s_w    = (unsigned short*)(smem + 38912);
    float*          s_s    = (float*)(smem + 61584);
    unsigned short* s_p    = (unsigned short*)(smem + 78992);
    unsigned short* s_q    = (unsigned short*)(smem + 98816);
    unsigned short* s_k    = (unsigned short*)(smem + 114176);
    unsigned short* s_vt   = (unsigned short*)(smem + 129536);
    float*          s_bias = (float*)(smem + 143360);
    unsigned short* s_h    = (unsigned short*)(smem + 98816);    // P6 alias
    unsigned short* s_w2   = (unsigned short*)(smem + 124416);   // P6 alias

    const int tid  = threadIdx.x;
    const int wid  = tid >> 6, lane = tid & 63, l16 = lane & 15, l4 = lane >> 4;
    const int wb   = blockIdx.x;
    const int b    = wb >> 10, wrem = wb & 1023, wy = wrem >> 5, wx = wrem & 31;
    const long base = ((long)(b*256 + wy*8)*256 + (long)(wx*8))*96;
    const int mtile = wid >> 1;      // row-tile for every GEMM phase
    const int nh    = wid & 1;       // column half

    // ---- Phase 0: x -> s_res ; rel-bias -> s_bias ; qkv^T -> s_w
    for (int i = tid; i < 64*24; i += 512) {
        int tok = i / 24, seg = i % 24;
        const float4 v = *reinterpret_cast<const float4*>(
            x + base + (long)(((tok >> 3) << 8) + (tok & 7))*96 + seg*4);
        *reinterpret_cast<float4*>(s_res + tok*100 + seg*4) = v;
    }
    for (int i = tid; i < 675; i += 512) s_bias[i] = btab[i];
    {
        uint4* dst = reinterpret_cast<uint4*>(s_w);
        const uint4* src = reinterpret_cast<const uint4*>(wbf);
        for (int i = tid; i < 288*12; i += 512) {
            int r = i / 12, sg = i % 12;
            dst[r*13 + sg] = src[r*12 + sg];
        }
    }
    __syncthreads();

    // ---- Phase 1: LN1 -> s_a (vectorized)
    {
        const int tok = tid >> 3, part = tid & 7;
        const float* rp = s_res + tok*100 + part*12;
        float4 v0 = *reinterpret_cast<const float4*>(rp);
        float4 v1 = *reinterpret_cast<const float4*>(rp + 4);
        float4 v2 = *reinterpret_cast<const float4*>(rp + 8);
        float r[12] = {v0.x,v0.y,v0.z,v0.w, v1.x,v1.y,v1.z,v1.w, v2.x,v2.y,v2.z,v2.w};
        float s1 = 0.f, s2 = 0.f;
        #pragma unroll
        for (int i = 0; i < 12; ++i) { s1 += r[i]; s2 += r[i]*r[i]; }
        s1 += __shfl_xor(s1,1); s2 += __shfl_xor(s2,1);
        s1 += __shfl_xor(s1,2); s2 += __shfl_xor(s2,2);
        s1 += __shfl_xor(s1,4); s2 += __shfl_xor(s2,4);
        float mu = s1*(1.f/96.f), var = s2*(1.f/96.f) - mu*mu;
        float rs = rsqrtf(var + 1e-5f);
        unsigned short* wp = s_a + tok*104 + part*12;
        #pragma unroll
        for (int q = 0; q < 3; ++q) {
            u16x4 pk;
            #pragma unroll
            for (int j = 0; j < 4; ++j) {
                int c = part*12 + q*4 + j;
                pk[j] = f2bf((r[q*4+j]-mu)*rs*n1g[c] + n1b[c]);
            }
            *reinterpret_cast<u16x4*>(wp + q*4) = pk;
        }
    }
    __syncthreads();

    // ---- Phase 2: QKV GEMM (64x288xK96), B from LDS
    {
        const unsigned short* ap = s_a + (mtile*16 + l16)*104 + l4*8;
        const bf16x8 a0 = LD8(ap), a1 = LD8(ap+32), a2 = LD8(ap+64);
        #pragma unroll
        for (int u = 0; u < 9; ++u) {
            const int ntile = nh*9 + u;
            const unsigned short* bp = s_w + (ntile*16 + l16)*104 + l4*8;
            f32x4 acc = {0.f,0.f,0.f,0.f};
            acc = MF(a0, LD8(bp),    acc);
            acc = MF(a1, LD8(bp+32), acc);
            acc = MF(a2, LD8(bp+64), acc);
            const int col = ntile*16 + l16;
            const float bv = qkv_b[col];
            const int sel = col/96, hc = col%96, h = hc >> 5, d = hc & 31;
            if (sel < 2) {
                unsigned short* q = (sel == 0 ? s_q : s_k) + h*2560 + d;
                #pragma unroll
                for (int r = 0; r < 4; ++r)
                    q[(mtile*16 + l4*4 + r)*40] = f2bf(acc[r] + bv);
            } else {
                u16x4 pk;
                #pragma unroll
                for (int r = 0; r < 4; ++r) pk[r] = f2bf(acc[r] + bv);
                *reinterpret_cast<u16x4*>(s_vt + h*2304 + d*72 + mtile*16 + l4*4) = pk;
            }
        }
    }
    __syncthreads();

    // ---- Phase 3: pipelined heads: {QK^T(h) || PV(h-1) || h0:proj^T stage} -> bar -> softmax(h) -> bar
    for (int h = 0; h < 3; ++h) {
        {   // QK^T head h, scale+bias folded into epilogue
            const unsigned short* ap = s_q + h*2560 + (mtile*16 + l16)*40 + l4*8;
            const bf16x8 af = LD8(ap);
            #pragma unroll
            for (int u = 0; u < 2; ++u) {
                const int ntile = nh*2 + u;
                const unsigned short* bp = s_k + h*2560 + (ntile*16 + l16)*40 + l4*8;
                f32x4 acc = {0.f,0.f,0.f,0.f};
                acc = MF(af, LD8(bp), acc);
                const int col = ntile*16 + l16;
                const int yj = col >> 3, xj = col & 7;
                #pragma unroll
                for (int r = 0; r < 4; ++r) {
                    const int row = mtile*16 + l4*4 + r;
                    const int yi = row >> 3, xi = row & 7;
                    const int ridx = (yi-yj+7)*15 + (xi-xj+7);
                    s_s[row*68 + col] = acc[r]*SCALE + s_bias[ridx*3 + h];
                }
            }
        }
        if (h == 0) {   // stage proj^T under first QK^T (disjoint regions, qkv^T dead)
            uint4* dst = reinterpret_cast<uint4*>(s_w);
            const uint4* src = reinterpret_cast<const uint4*>(wbf) + 3456;
            for (int i = tid; i < 96*12; i += 512) {
                int r = i/12, sg = i%12;
                dst[r*13 + sg] = src[r*12 + sg];
            }
        } else {        // PV head h-1 (overlaps with QK^T h)
            const unsigned short* ap = s_p + (mtile*16 + l16)*72 + l4*8;
            const bf16x8 a0 = LD8(ap), a1 = LD8(ap+32);
            const unsigned short* bp = s_vt + (h-1)*2304 + (nh*16 + l16)*72 + l4*8;
            f32x4 acc = {0.f,0.f,0.f,0.f};
            acc = MF(a0, LD8(bp),    acc);
            acc = MF(a1, LD8(bp+32), acc);
            #pragma unroll
            for (int r = 0; r < 4; ++r)
                s_a[(mtile*16 + l4*4 + r)*104 + (h-1)*32 + nh*16 + l16] = f2bf(acc[r]);
        }
        __syncthreads();
        {   // softmax head h (vectorized reads, one 16B P write)
            const int i = tid >> 3, part = tid & 7;
            const float* sp = s_s + i*68 + part*8;
            float4 v0 = *reinterpret_cast<const float4*>(sp);
            float4 v1 = *reinterpret_cast<const float4*>(sp + 4);
            float v[8] = {v0.x,v0.y,v0.z,v0.w, v1.x,v1.y,v1.z,v1.w};
            float m = v[0];
            #pragma unroll
            for (int u = 1; u < 8; ++u) m = fmaxf(m, v[u]);
            m = fmaxf(m, __shfl_xor(m,1)); m = fmaxf(m, __shfl_xor(m,2)); m = fmaxf(m, __shfl_xor(m,4));
            float s = 0.f;
            #pragma unroll
            for (int u = 0; u < 8; ++u) { v[u] = __expf(v[u] - m); s += v[u]; }
            s += __shfl_xor(s,1); s += __shfl_xor(s,2); s += __shfl_xor(s,4);
            const float inv = 1.f/s;
            u16x8 pk;
            #pragma unroll
            for (int u = 0; u < 8; ++u) pk[u] = f2bf(v[u]*inv);
            *reinterpret_cast<u16x8*>(s_p + i*72 + part*8) = pk;
        }
        __syncthreads();
    }
    {   // PV head 2 (epilogue of the pipeline)
        const unsigned short* ap = s_p + (mtile*16 + l16)*72 + l4*8;
        const bf16x8 a0 = LD8(ap), a1 = LD8(ap+32);
        const unsigned short* bp = s_vt + 2*2304 + (nh*16 + l16)*72 + l4*8;
        f32x4 acc = {0.f,0.f,0.f,0.f};
        acc = MF(a0, LD8(bp),    acc);
        acc = MF(a1, LD8(bp+32), acc);
        #pragma unroll
        for (int r = 0; r < 4; ++r)
            s_a[(mtile*16 + l4*4 + r)*104 + 2*32 + nh*16 + l16] = f2bf(acc[r]);
    }
    __syncthreads();

    // ---- Phase 4: proj (64x96xK96) + residual -> s_res becomes x1
    {
        const unsigned short* ap = s_a + (mtile*16 + l16)*104 + l4*8;
        const bf16x8 a0 = LD8(ap), a1 = LD8(ap+32), a2 = LD8(ap+64);
        #pragma unroll
        for (int u = 0; u < 3; ++u) {
            const int ntile = nh*3 + u;
            const unsigned short* bp = s_w + (ntile*16 + l16)*104 + l4*8;
            f32x4 acc = {0.f,0.f,0.f,0.f};
            acc = MF(a0, LD8(bp),    acc);
            acc = MF(a1, LD8(bp+32), acc);
            acc = MF(a2, LD8(bp+64), acc);
            const int c = ntile*16 + l16;
            const float pb = proj_b[c];
            #pragma unroll
            for (int r = 0; r < 4; ++r) {
                const int tok = mtile*16 + l4*4 + r;
                s_res[tok*100 + c] += acc[r] + pb;
            }
        }
    }
    __syncthreads();

    // ---- Phase 5: LN2 -> s_a (vectorized) ; stage fc1-ch0 + fc2-ch0
    {
        const int tok = tid >> 3, part = tid & 7;
        const float* rp = s_res + tok*100 + part*12;
        float4 v0 = *reinterpret_cast<const float4*>(rp);
        float4 v1 = *reinterpret_cast<const float4*>(rp + 4);
        float4 v2 = *reinterpret_cast<const float4*>(rp + 8);
        float r[12] = {v0.x,v0.y,v0.z,v0.w, v1.x,v1.y,v1.z,v1.w, v2.x,v2.y,v2.z,v2.w};
        float s1 = 0.f, s2 = 0.f;
        #pragma unroll
        for (int i = 0; i < 12; ++i) { s1 += r[i]; s2 += r[i]*r[i]; }
        s1 += __shfl_xor(s1,1); s2 += __shfl_xor(s2,1);
        s1 += __shfl_xor(s1,2); s2 += __shfl_xor(s2,2);
        s1 += __shfl_xor(s1,4); s2 += __shfl_xor(s2,4);
        float mu = s1*(1.f/96.f), var = s2*(1.f/96.f) - mu*mu;
        float rs = rsqrtf(var + 1e-5f);
        unsigned short* wp = s_a + tok*104 + part*12;
        #pragma unroll
        for (int q = 0; q < 3; ++q) {
            u16x4 pk;
            #pragma unroll
            for (int j = 0; j < 4; ++j) {
                int c = part*12 + q*4 + j;
                pk[j] = f2bf((r[q*4+j]-mu)*rs*n2g[c] + n2b[c]);
            }
            *reinterpret_cast<u16x4*>(wp + q*4) = pk;
        }
    }

    // ---- Phase 6: MLP in 2 hidden chunks of 192, weights staged in LDS
    f32x4 macc[3];
    #pragma unroll
    for (int u = 0; u < 3; ++u) macc[u] = (f32x4){0.f,0.f,0.f,0.f};

    for (int ch = 0; ch < 2; ++ch) {
        {   // stage fc1 chunk [192][104] and fc2 chunk [96][200]
            uint4* d1 = reinterpret_cast<uint4*>(s_w);
            uint4* d2 = reinterpret_cast<uint4*>(s_w2);
            const uint4* src = reinterpret_cast<const uint4*>(wbf);
            for (int i = tid; i < 192*12; i += 512) {
                int r = i/12, sg = i%12;
                d1[r*13 + sg] = src[4608 + (ch*192 + r)*12 + sg];
            }
            for (int i = tid; i < 96*24; i += 512) {
                int n = i/24, sg = i%24;
                d2[n*25 + sg] = src[9216 + n*48 + ch*24 + sg];
            }
        }
        __syncthreads();
        {   // fc1 (64x192xK96) + sigmoid-form GELU -> s_h
            const unsigned short* ap = s_a + (mtile*16 + l16)*104 + l4*8;
            const bf16x8 a0 = LD8(ap), a1 = LD8(ap+32), a2 = LD8(ap+64);
            #pragma unroll
            for (int u = 0; u < 6; ++u) {
                const int ntile = nh*6 + u;
                const int hcol = ntile*16 + l16;
                const unsigned short* bp = s_w + hcol*104 + l4*8;
                f32x4 acc = {0.f,0.f,0.f,0.f};
                acc = MF(a0, LD8(bp),    acc);
                acc = MF(a1, LD8(bp+32), acc);
                acc = MF(a2, LD8(bp+64), acc);
                const float fb = fc1b[ch*192 + hcol];
                #pragma unroll
                for (int r = 0; r < 4; ++r) {
                    float v = acc[r] + fb;
                    float g = v / (1.f + __expf(-1.5957691216057308f*(v + 0.044715f*v*v*v)));
                    s_h[(mtile*16 + l4*4 + r)*200 + hcol] = f2bf(g);
                }
            }
        }
        __syncthreads();
        {   // fc2 partial (64x96xK192), accumulate across chunks
            const unsigned short* ap = s_h + (mtile*16 + l16)*200 + l4*8;
            bf16x8 af[6];
            #pragma unroll
            for (int kc = 0; kc < 6; ++kc) af[kc] = LD8(ap + kc*32);
            #pragma unroll
            for (int u = 0; u < 3; ++u) {
                const unsigned short* bp = s_w2 + ((nh*3 + u)*16 + l16)*200 + l4*8;
                #pragma unroll
                for (int kc = 0; kc < 6; ++kc)
                    macc[u] = MF(af[kc], LD8(bp + kc*32), macc[u]);
            }
        }
        __syncthreads();   // fc2 reads done before ch1 restage (and s_h rewrite)
    }

    // ---- final: out = x1 + mlp + fc2_b
    {
        #pragma unroll
        for (int u = 0; u < 3; ++u) {
            const int c = (nh*3 + u)*16 + l16;
            const float fb = fc2b[c];
            #pragma unroll
            for (int r = 0; r < 4; ++r) {
                const int tok = mtile*16 + l4*4 + r;
                out[base + (long)(((tok >> 3) << 8) + (tok & 7))*96 + c] =
                    s_res[tok*100 + c] + macc[u][r] + fb;
            }
        }
    }
}

extern "C" void kernel_launch(void* const* d_in, const int* in_sizes, int n_in,
                              void* d_out, int out_size, void* d_ws, size_t ws_size,
                              hipStream_t stream) {
    (void)in_sizes; (void)n_in; (void)out_size; (void)ws_size;
    const float* x     = (const float*)d_in[0];
    const float* n1g   = (const float*)d_in[1];
    const float* n1b   = (const float*)d_in[2];
    const float* qkvw  = (const float*)d_in[3];
    const float* qkvb  = (const float*)d_in[4];
    const float* projw = (const float*)d_in[5];
    const float* projb = (const float*)d_in[6];
    const float* btab  = (const float*)d_in[7];
    const float* n2g   = (const float*)d_in[8];
    const float* n2b   = (const float*)d_in[9];
    const float* fc1w  = (const float*)d_in[10];
    const float* fc1b  = (const float*)d_in[11];
    const float* fc2w  = (const float*)d_in[12];
    const float* fc2b  = (const float*)d_in[13];
    float* out = (float*)d_out;
    unsigned short* ws = (unsigned short*)d_ws;

    hipFuncSetAttribute(reinterpret_cast<const void*>(k_fused),
                        hipFuncAttributeMaxDynamicSharedMemorySize, 162816);

    k_prep<<<dim3(216), dim3(512), 0, stream>>>(qkvw, projw, fc1w, fc2w, ws);
    k_fused<<<dim3(NWIN), dim3(512), 162816, stream>>>(
        x, n1g, n1b, qkvb, projb, btab, n2g, n2b, fc1b, fc2b, ws, out);
}